// Round 2
// baseline (540.962 us; speedup 1.0000x reference)
//
#include <hip/hip_runtime.h>

// out (176, 192, 56, 56) fp32:
//   out[:, :64]  = x (176, 64, 56, 56)
//   out[:, 64:]  = y (176, 128, 28, 28) nearest-upsampled x2
// Pure HBM-bound: ~636 MB moved -> ~101 us floor at 6.3 TB/s.
//
// R1/R2: grid-stride with capped grid (2048 blocks = 8 blocks/CU, all
// resident). R0 launched 103,488 tiny WGs (~10 KB of traffic each, ~250 ns
// at roofline) -> workgroup dispatch rate became the limiter (~2.5 TB/s
// effective). The rocclr fill kernel hits 6.28 TB/s at 9.9% occupancy with
// exactly this capped-grid + internal-loop structure.
// (R1 bench run failed at the container level — infra flake, not kernel;
// this is a clean re-run of the same experiment.)

#define NB   176
#define C1   64
#define C2   128
#define HH   56
#define WW   56
#define H2   28
#define W2   28
#define CT   (C1 + C2)          // 192
#define VPR  (WW / 4)           // 14 float4 per output row
#define NROWS (NB * CT * HH)    // 1,892,352 rows
#define NVEC  (NROWS * VPR)     // 26,492,928 float4 stores

#define NTHR 256
#define NBLK 2048               // 8 blocks/CU * 256 CUs; 32 waves/CU resident

__global__ __launch_bounds__(NTHR) void upcat_kernel(
    const float* __restrict__ x,
    const float* __restrict__ y,
    float* __restrict__ out)
{
    const unsigned stride = NBLK * NTHR;
    for (unsigned i = blockIdx.x * NTHR + threadIdx.x; i < NVEC; i += stride) {
        unsigned r  = i / VPR;       // output row id: (b, c, h)
        unsigned j  = i - r * VPR;   // float4 slot within row
        unsigned w0 = j * 4;

        unsigned h  = r % HH;
        unsigned bc = r / HH;
        unsigned c  = bc % CT;
        unsigned b  = bc / CT;

        float4 v;
        if (c < C1) {
            // straight copy from x, 16B-aligned (w0 % 4 == 0)
            const float4* px = (const float4*)(x + ((b * C1 + c) * HH + h) * WW + w0);
            v = *px;
        } else {
            // nearest upsample: out[w0..w0+3] = y[w0/2], y[w0/2], y[w0/2+1], y[w0/2+1]
            unsigned c2 = c - C1;
            const float2* py = (const float2*)(y + ((b * C2 + c2) * H2 + (h >> 1)) * W2 + (w0 >> 1));
            float2 u = *py;
            v = make_float4(u.x, u.x, u.y, u.y);
        }

        float4* po = (float4*)(out + r * WW + w0);
        *po = v;
    }
}

extern "C" void kernel_launch(void* const* d_in, const int* in_sizes, int n_in,
                              void* d_out, int out_size, void* d_ws, size_t ws_size,
                              hipStream_t stream) {
    const float* x = (const float*)d_in[0];
    const float* y = (const float*)d_in[1];
    float* out = (float*)d_out;

    upcat_kernel<<<NBLK, NTHR, 0, stream>>>(x, y, out);
}